// Round 8
// baseline (408.445 us; speedup 1.0000x reference)
//
#include <hip/hip_runtime.h>

#define KNEIGH 16
#define FDIM   128
#define NSLICE 4
#define SLICE_SHIFT 17   // 500000 nodes -> 4 slices of 131072 rows (64 MB)

typedef float f32x4 __attribute__((ext_vector_type(4)));

// R4 structure (best known: 351 us): one HALF-WAVE (32 lanes) per batch row,
// wave covers rows {2r, 2r+1}; each lane owns one float4 slice; every
// global_load_dwordx4 covers two 512 B feature rows; scalar (SGPR) control
// path; zero cross-lane data movement.
//
// NEW: feature-slice multi-pass. The kernel is launched NSLICE times; pass s
// gathers only neighbors with idx in slice s (idx>>17 == s) and accumulates
// into out (pass 0 initializes, later passes read-modify-write). Per pass
// the gather working set is ~51 MB of unique rows -> L3-resident + TLB-dense,
// so duplicate touches become cache hits. This attacks the measured wall
// (random-gather latency x ~64 MSHR/CU), which structure tuning (R4/R5/R7)
// proved insensitive to occupancy and per-wave load depth.
__global__ __launch_bounds__(256) void WeightedAggregator_89489938580183_kernel(
    const float* __restrict__ features,   // [N, 128]
    const float* __restrict__ neigh_w,    // [B, 16]
    const int*   __restrict__ neigh_idx,  // [B, 16] (int32 per harness)
    float*       __restrict__ out,        // [B, 128]
    int batch, int slice) {

    const int lane = threadIdx.x & 63;
    int wid = blockIdx.x * (blockDim.x >> 6) + (threadIdx.x >> 6);
    int rowA = wid * 2;
    if (rowA >= batch) return;
    rowA = __builtin_amdgcn_readfirstlane(rowA);       // wave-uniform
    const int rowB = (rowA + 1 < batch) ? rowA + 1 : rowA;  // tail clamp

    const int half = lane >> 5;   // 0 -> rowA, 1 -> rowB
    const int sub  = lane & 31;   // float4 column quad owned
    const int orow = rowA + half;

    // Issue the previous-partial read early (slice>0): its latency hides
    // under the scalar loads + gather issue below.
    f32x4 prev = (f32x4)(0.0f);
    if (slice != 0 && orow < batch) {
        prev = ((const f32x4*)out)[((size_t)orow << 5) + sub];
    }

    // Scalar (SGPR) loads: two rows' weights / indices.
    const float* wpA = neigh_w   + (size_t)rowA * KNEIGH;
    const float* wpB = neigh_w   + (size_t)rowB * KNEIGH;
    const int*   ipA = neigh_idx + (size_t)rowA * KNEIGH;
    const int*   ipB = neigh_idx + (size_t)rowB * KNEIGH;

    float wA[KNEIGH], wB[KNEIGH];
    int   iA[KNEIGH], iB[KNEIGH];
    #pragma unroll
    for (int k = 0; k < KNEIGH; ++k) {
        wA[k] = wpA[k]; wB[k] = wpB[k];
        iA[k] = ipA[k]; iB[k] = ipB[k];
    }

    // Uniform per-row weight sums (full sum every pass -- normalization is
    // pass-invariant).
    float sA = wA[0], sB = wB[0];
    #pragma unroll
    for (int k = 1; k < KNEIGH; ++k) { sA += wA[k]; sB += wB[k]; }
    const float inv = half ? (1.0f / sB) : (1.0f / sA);

    // Dual accumulators break the serial FMA dependence chain.
    f32x4 acc0 = (f32x4)(0.0f);
    f32x4 acc1 = (f32x4)(0.0f);

    #pragma unroll
    for (int k = 0; k < KNEIGH; k += 2) {
        const int   i0 = half ? iB[k]     : iA[k];
        const int   i1 = half ? iB[k + 1] : iA[k + 1];
        const float w0 = (half ? wB[k]     : wA[k])     * inv;
        const float w1 = (half ? wB[k + 1] : wA[k + 1]) * inv;

        // Half-wave-uniform predicates: cheap exec-mask skip, no memory
        // request issued for out-of-slice neighbors.
        if (((unsigned)i0 >> SLICE_SHIFT) == (unsigned)slice) {
            const f32x4 f0 = ((const f32x4*)features)[((unsigned)i0 << 5) + sub];
            acc0 += w0 * f0;
        }
        if (((unsigned)i1 >> SLICE_SHIFT) == (unsigned)slice) {
            const f32x4 f1 = ((const f32x4*)features)[((unsigned)i1 << 5) + sub];
            acc1 += w1 * f1;
        }
    }

    const f32x4 acc = prev + acc0 + acc1;

    // 1 KB fully-coalesced wave store (rows 2r, 2r+1 contiguous).
    if (orow < batch) {
        ((f32x4*)out)[((size_t)orow << 5) + sub] = acc;
    }
}

extern "C" void kernel_launch(void* const* d_in, const int* in_sizes, int n_in,
                              void* d_out, int out_size, void* d_ws, size_t ws_size,
                              hipStream_t stream) {
    const float* features  = (const float*)d_in[0];
    const float* neigh_w   = (const float*)d_in[1];
    const int*   neigh_idx = (const int*)d_in[2];
    float*       out       = (float*)d_out;

    const int batch = in_sizes[1] / KNEIGH;      // 50000

    // One wave per TWO rows; 4 waves per 256-thread block.
    const int rows_per_block = 2 * (256 / 64);
    const int blocks = (batch + rows_per_block - 1) / rows_per_block;

    // Stream-ordered multi-pass: pass s gathers only feature slice s.
    // Kernel-boundary release/acquire makes each pass's out-writes visible
    // to the next (cross-XCD safe).
    for (int s = 0; s < NSLICE; ++s) {
        WeightedAggregator_89489938580183_kernel<<<blocks, 256, 0, stream>>>(
            features, neigh_w, neigh_idx, out, batch, s);
    }
}

// Round 15
// 398.024 us; speedup vs baseline: 1.0262x; 1.0262x over previous
//
#include <hip/hip_runtime.h>

#define KNEIGH 16
#define FDIM   128
#define NSLICE 4
#define SLICE_SHIFT 17          // 500000 nodes -> 4 slices of 131072 rows (64 MB)
#define NBLOCKS 2048            // x4 waves = 8192 waves, exactly co-resident
#define NWAVES  (NBLOCKS * 4)

typedef float f32x4 __attribute__((ext_vector_type(4)));

// Per-(pair, slice) contribution. R4 gather structure: half-wave (32 lanes)
// per row, lane owns one float4 slice, dwordx4 covers two 512 B rows.
// Scalar (SGPR) control path: `pair` is wave-uniform, so w/idx load via
// s_load; the slice predicate is half-wave-uniform -> cheap exec-mask skip.
__device__ __forceinline__ f32x4 slice_contrib(
    const float* __restrict__ features,
    const float* __restrict__ neigh_w,
    const int*   __restrict__ neigh_idx,
    int pair, int batch, int half, int sub, unsigned slice) {

    const int r0 = pair * 2;
    const int r1 = (r0 + 1 < batch) ? r0 + 1 : r0;   // tail clamp
    const float* wp0 = neigh_w   + (size_t)r0 * KNEIGH;
    const float* wp1 = neigh_w   + (size_t)r1 * KNEIGH;
    const int*   ip0 = neigh_idx + (size_t)r0 * KNEIGH;
    const int*   ip1 = neigh_idx + (size_t)r1 * KNEIGH;

    float w0[KNEIGH], w1[KNEIGH]; int i0[KNEIGH], i1[KNEIGH];
    #pragma unroll
    for (int k = 0; k < KNEIGH; ++k) {
        w0[k] = wp0[k]; w1[k] = wp1[k];
        i0[k] = ip0[k]; i1[k] = ip1[k];
    }
    float s0 = w0[0], s1 = w1[0];
    #pragma unroll
    for (int k = 1; k < KNEIGH; ++k) { s0 += w0[k]; s1 += w1[k]; }
    const float inv = half ? (1.0f / s1) : (1.0f / s0);

    f32x4 a0 = (f32x4)(0.0f);
    f32x4 a1 = (f32x4)(0.0f);
    #pragma unroll
    for (int k = 0; k < KNEIGH; k += 2) {
        const int   iA = half ? i1[k]     : i0[k];
        const int   iB = half ? i1[k + 1] : i0[k + 1];
        const float wA = (half ? w1[k]     : w0[k])     * inv;
        const float wB = (half ? w1[k + 1] : w0[k + 1]) * inv;
        if (((unsigned)iA >> SLICE_SHIFT) == slice)
            a0 += wA * ((const f32x4*)features)[((unsigned)iA << 5) + sub];
        if (((unsigned)iB >> SLICE_SHIFT) == slice)
            a1 += wB * ((const f32x4*)features)[((unsigned)iB << 5) + sub];
    }
    return a0 + a1;
}

// Persistent-grid slice-phased gather. Each wave owns up to FOUR row-pairs
// (wid + j*8192, j=0..3 -> 32768 >= 25000 pairs: full coverage, fixing R9's
// bug where pairs 16384..24999 were never written). Accumulators are four
// NAMED registers (static indexing, no scratch) held across all 4 slice
// phases -- zero extra HBM traffic vs R8's out-RMW scheme. Per phase the
// whole co-resident grid gathers from one 64 MB feature slice, so the 1.6x
// index reuse resolves in L2/L3 instead of repeat HBM fetches.
__global__ __launch_bounds__(256) void WeightedAggregator_89489938580183_kernel(
    const float* __restrict__ features,   // [N, 128]
    const float* __restrict__ neigh_w,    // [B, 16]
    const int*   __restrict__ neigh_idx,  // [B, 16] (int32 per harness)
    float*       __restrict__ out,        // [B, 128]
    int batch) {

    const int lane = threadIdx.x & 63;
    const int wid0 = blockIdx.x * (blockDim.x >> 6) + (threadIdx.x >> 6);
    const int wid  = __builtin_amdgcn_readfirstlane(wid0);

    const int half = lane >> 5;   // 0 -> even row of pair, 1 -> odd row
    const int sub  = lane & 31;   // float4 column quad owned

    const int npairs = (batch + 1) >> 1;       // 25000
    const int p0 = wid;
    const int p1 = wid + NWAVES;
    const int p2 = wid + 2 * NWAVES;
    const int p3 = wid + 3 * NWAVES;

    f32x4 a0 = (f32x4)(0.0f);
    f32x4 a1 = (f32x4)(0.0f);
    f32x4 a2 = (f32x4)(0.0f);
    f32x4 a3 = (f32x4)(0.0f);

    for (unsigned s = 0; s < NSLICE; ++s) {
        if (p0 < npairs)
            a0 += slice_contrib(features, neigh_w, neigh_idx, p0, batch, half, sub, s);
        if (p1 < npairs)
            a1 += slice_contrib(features, neigh_w, neigh_idx, p1, batch, half, sub, s);
        if (p2 < npairs)
            a2 += slice_contrib(features, neigh_w, neigh_idx, p2, batch, half, sub, s);
        if (p3 < npairs)
            a3 += slice_contrib(features, neigh_w, neigh_idx, p3, batch, half, sub, s);
    }

    // Coalesced 1 KB wave stores (pair rows contiguous).
    if (p0 < npairs) {
        const int orow = p0 * 2 + half;
        if (orow < batch) ((f32x4*)out)[((size_t)orow << 5) + sub] = a0;
    }
    if (p1 < npairs) {
        const int orow = p1 * 2 + half;
        if (orow < batch) ((f32x4*)out)[((size_t)orow << 5) + sub] = a1;
    }
    if (p2 < npairs) {
        const int orow = p2 * 2 + half;
        if (orow < batch) ((f32x4*)out)[((size_t)orow << 5) + sub] = a2;
    }
    if (p3 < npairs) {
        const int orow = p3 * 2 + half;
        if (orow < batch) ((f32x4*)out)[((size_t)orow << 5) + sub] = a3;
    }
}

extern "C" void kernel_launch(void* const* d_in, const int* in_sizes, int n_in,
                              void* d_out, int out_size, void* d_ws, size_t ws_size,
                              hipStream_t stream) {
    const float* features  = (const float*)d_in[0];
    const float* neigh_w   = (const float*)d_in[1];
    const int*   neigh_idx = (const int*)d_in[2];
    float*       out       = (float*)d_out;

    const int batch = in_sizes[1] / KNEIGH;      // 50000

    WeightedAggregator_89489938580183_kernel<<<NBLOCKS, 256, 0, stream>>>(
        features, neigh_w, neigh_idx, out, batch);
}